// Round 4
// baseline (136.402 us; speedup 1.0000x reference)
//
#include <hip/hip_runtime.h>

// 16x16 output tile per block, 256 threads (4 waves). Small tiles -> ~784 heavy
// blocks (~3 resident/CU) so heavy-block stalls overlap across blocks; 9.1 KB LDS
// keeps residency wave-limited at 8 blocks/CU (launch_bounds(256,8) caps VGPR<=64).
// img_p (padded img + noise) needed at radius 3  -> 22x22 per channel
// img_r needed at radius 2                        -> 20x20
// img_3d_mod needed at radius 1                   -> 18x18
#define TS 16
#define PW 22
#define PS 23   // LDS row stride (pad +1)
#define RW 20
#define RS 21
#define MW 18
#define MS 19

__global__ __launch_bounds__(256, 8)
void gdfn_kernel(const float* __restrict__ img,
                 const float* __restrict__ noise,
                 const float* __restrict__ re_mask,
                 const int*   __restrict__ sel,
                 const int*   __restrict__ mix_sel,
                 float*       __restrict__ out)
{
    constexpr int H = 512, W = 512, C = 3, HP = 514, WP = 514;
    const int b   = blockIdx.z;
    const int h0  = blockIdx.y * TS;
    const int w0  = blockIdx.x * TS;
    const int tid = threadIdx.x;

    const size_t HWs  = (size_t)H * W;
    const size_t imgB = (size_t)b * C * HWs;
    const size_t noiB = (size_t)b * C * HP * WP;

    // Copy mapping: tile is 16x16x3 = 192 float4s; threads 0..191 move one each.
    // c = tid/64, r = tid%64 -> row r>>2, cols ((r&3)*4 .. +3). 64B-coalesced rows.
    const int cc   = tid >> 6;            // 0..3 (3 inactive)
    const int rr   = tid & 63;
    const int cty  = rr >> 2;
    const int ctx4 = (rr & 3) << 2;
    const size_t cpo = imgB + (size_t)cc * HWs + (size_t)(h0 + cty) * W + (w0 + ctx4);

    // ---- fast path 1: batch not selected -> out = img ----
    if (!sel[b]) {
        if (cc < 3) *(float4*)(out + cpo) = *(const float4*)(img + cpo);
        return;
    }

    // ---- load img + re_mask tiles; fast path 2: mask all ones ----
    float4 vimg4 = make_float4(0.f, 0.f, 0.f, 0.f);
    int allone = 1;
    if (cc < 3) {
        vimg4 = *(const float4*)(img + cpo);
        float4 r = *(const float4*)(re_mask + cpo);
        allone = (r.x == 1.0f) & (r.y == 1.0f) & (r.z == 1.0f) & (r.w == 1.0f);
    }
    allone = __syncthreads_and(allone);
    if (allone) {
        if (cc < 3) *(float4*)(out + cpo) = vimg4;
        return;
    }

    // ---- heavy path (~784 blocks: tiles overlapping the erase rect, sel batches) ----
    const int ty = tid >> 4, tx = tid & 15;   // 1 px/thread for stage 3
    const int gy = h0 + ty, gx = w0 + tx;
    const size_t p3 = imgB + (size_t)gy * W + gx;

    // Issue stage-3 per-pixel loads NOW so they overlap stages 0-2 (L2-warm).
    float img3[3], rm3[3];
#pragma unroll
    for (int c = 0; c < 3; ++c) {
        img3[c] = img[p3 + c * HWs];
        rm3[c]  = re_mask[p3 + c * HWs];
    }

    __shared__ float s_imgp[3 * PW * PS];  // padded img + noise, radius 3  (6072 B)
    __shared__ float s_imgr[RW * RS];      // weighted local mean, radius 2 (1680 B)
    __shared__ float s_mod [MW * MS];      // selected weight, radius 1     (1368 B)

    // Stage 0: img_p = pad(img,1) + noise over padded rows/cols [h0-2, h0+TS+3].
#pragma unroll
    for (int it = 0; it < 6; ++it) {
        int idx = tid + it * 256;
        if (idx < 3 * PW * PW) {
            int c  = idx / (PW * PW);
            int r  = idx - c * (PW * PW);
            int ly = r / PW, lx = r - ly * PW;
            int py = h0 - 2 + ly, px = w0 - 2 + lx;   // padded-image coords
            float v = 0.f;
            if (py >= 0 && py < HP && px >= 0 && px < WP) {
                v = noise[noiB + (size_t)c * HP * WP + (size_t)py * WP + px];
                int iy = py - 1, ix = px - 1;
                if (iy >= 0 && iy < H && ix >= 0 && ix < W)
                    v += img[imgB + (size_t)c * HWs + (size_t)iy * W + ix];
            }
            s_imgp[c * PW * PS + ly * PS + lx] = v;
        }
    }
    __syncthreads();

    // Stage 1: img_r over tile+2 halo.
    // w = exp(-(x-mean)^2/(2*std^2)), std^2(ddof=1) = ssd/8  =>  exp(-4 d^2/ssd)
#pragma unroll
    for (int it = 0; it < 2; ++it) {
        int idx = tid + it * 256;
        if (idx >= RW * RW) continue;
        int sy = idx / RW, sx = idx - sy * RW;
        int ry = h0 - 2 + sy, rx = w0 - 2 + sx;
        if (ry < 0 || ry >= H || rx < 0 || rx >= W) continue;
        float v[3][9], w3[9];
#pragma unroll
        for (int c = 0; c < 3; ++c) {
            const float* sp = &s_imgp[c * PW * PS + sy * PS + sx];
            float sum = 0.f;
#pragma unroll
            for (int i = 0; i < 3; ++i)
#pragma unroll
                for (int j = 0; j < 3; ++j) {
                    float x = sp[i * PS + j];
                    v[c][i * 3 + j] = x;
                    sum += x;
                }
            float mean = sum * (1.f / 9.f);
            float ssd = 0.f;
#pragma unroll
            for (int k = 0; k < 9; ++k) { float d = v[c][k] - mean; ssd += d * d; }
            float inv = -4.f / ssd;
#pragma unroll
            for (int k = 0; k < 9; ++k) {
                float d  = v[c][k] - mean;
                float wv = expf(d * d * inv);
                w3[k] = (c == 0) ? wv : fminf(w3[k], wv);
            }
        }
        float num = 0.f, den = 0.f;
#pragma unroll
        for (int k = 0; k < 9; ++k) {
            den += w3[k];
            num += (v[0][k] + v[1][k] + v[2][k]) * w3[k];
        }
        s_imgr[sy * RS + sx] = num / den;
    }
    __syncthreads();

    const int msel = mix_sel[b];

    // Stage 2: first-occurrence argmin/argmax over img_r 3x3 (OOB = 0.0 exactly),
    // then recompute the selected weight img_3d[q][k_sel].
#pragma unroll
    for (int it = 0; it < 2; ++it) {
        int idx = tid + it * 256;
        if (idx >= MW * MW) continue;
        int my = idx / MW, mx = idx - my * MW;
        int qy = h0 - 1 + my, qx = w0 - 1 + mx;
        if (qy < 0 || qy >= H || qx < 0 || qx >= W) continue;
        float bmin = 0.f, bmax = 0.f;
        int imin = 0, imax = 0;
#pragma unroll
        for (int k = 0; k < 9; ++k) {
            int di = k / 3 - 1, dj = k % 3 - 1;
            int ny = qy + di, nx = qx + dj;
            float val = 0.f;
            if (ny >= 0 && ny < H && nx >= 0 && nx < W)
                val = s_imgr[(my + 1 + di) * RS + (mx + 1 + dj)];
            if (k == 0) { bmin = val; bmax = val; }
            else {
                if (val < bmin) { bmin = val; imin = k; }
                if (val > bmax) { bmax = val; imax = k; }
            }
        }
        int ks = msel ? imax : imin;
        int si = ks / 3, sj = ks % 3;
        float wmin = 1e30f;
#pragma unroll
        for (int c = 0; c < 3; ++c) {
            const float* sp = &s_imgp[c * PW * PS + (my + 1) * PS + (mx + 1)];
            float vv[9];
            float sum = 0.f;
#pragma unroll
            for (int i = 0; i < 3; ++i)
#pragma unroll
                for (int j = 0; j < 3; ++j) {
                    float x = sp[i * PS + j];
                    vv[i * 3 + j] = x;
                    sum += x;
                }
            float mean = sum * (1.f / 9.f);
            float ssd = 0.f;
#pragma unroll
            for (int k = 0; k < 9; ++k) { float d = vv[k] - mean; ssd += d * d; }
            float d  = vv[si * 3 + sj] - mean;
            float wv = expf(d * d * (-4.f / ssd));
            wmin = fminf(wmin, wv);
        }
        s_mod[my * MS + mx] = wmin;
    }
    __syncthreads();

    // Stage 3: img_mod = sum(img_e * m_e)/sum(m_e) per channel, then blend. 1 px/thread.
    float m[9];
    float mden = 0.f;
#pragma unroll
    for (int k = 0; k < 9; ++k) {
        int di = k / 3 - 1, dj = k % 3 - 1;
        int ny = gy + di, nx = gx + dj;
        float mv = 0.f;
        if (ny >= 0 && ny < H && nx >= 0 && nx < W)
            mv = s_mod[(ty + di + 1) * MS + (tx + dj + 1)];
        m[k] = mv;
        mden += mv;
    }
#pragma unroll
    for (int c = 0; c < 3; ++c) {
        const float* sp = &s_imgp[c * PW * PS + (ty + 2) * PS + (tx + 2)];
        float numc = 0.f;
#pragma unroll
        for (int i = 0; i < 3; ++i)
#pragma unroll
            for (int j = 0; j < 3; ++j)
                numc += sp[i * PS + j] * m[i * 3 + j];
        float imod = numc / mden;
        float rm   = rm3[c];
        out[p3 + c * HWs] = imod * (1.f - rm) + img3[c] * rm;
    }
}

extern "C" void kernel_launch(void* const* d_in, const int* in_sizes, int n_in,
                              void* d_out, int out_size, void* d_ws, size_t ws_size,
                              hipStream_t stream)
{
    const float* img     = (const float*)d_in[0];
    const float* noise   = (const float*)d_in[1];
    const float* re_mask = (const float*)d_in[2];
    const int*   sel     = (const int*)d_in[3];
    const int*   mix_sel = (const int*)d_in[4];
    float*       out     = (float*)d_out;

    const int B = in_sizes[3];          // 8
    dim3 grid(512 / TS, 512 / TS, B);   // 32 x 32 x 8
    dim3 block(256);
    hipLaunchKernelGGL(gdfn_kernel, grid, block, 0, stream,
                       img, noise, re_mask, sel, mix_sel, out);
}

// Round 5
// 134.075 us; speedup vs baseline: 1.0174x; 1.0174x over previous
//
#include <hip/hip_runtime.h>

// Two-kernel split:
//  A) copy_kernel: grid-stride float4 memcpy img->out for ALL pixels at streaming BW.
//  B) gdfn_heavy: 8x8 tiles, 256 threads; exits unless (sel && mask has a zero).
//     Heavy region ~2704 blocks x 4 waves = ~33 waves/CU -> full occupancy
//     (R4's 16x16/256 gave only 10.6 waves/CU during the heavy phase).
//     Stage 1 is (pixel,channel)-parallel: 3x threads, 9 expf per task instead of 27.
//     w3[9] cached in LDS so stage 2 is 1 LDS read (bit-identical to recompute).
// img_p (padded img + noise) radius 3 -> 14x14/ch; img_r radius 2 -> 12x12;
// img_3d_mod radius 1 -> 10x10.
#define TS 8
#define PW 14
#define PS 15   // LDS row stride (pad +1)
#define RW 12
#define RS 13
#define MW 10
#define MS 11

__global__ __launch_bounds__(256)
void copy_kernel(const float4* __restrict__ src, float4* __restrict__ dst, int n4)
{
    int i = blockIdx.x * 256 + threadIdx.x;
    const int stride = gridDim.x * 256;
    for (; i < n4; i += stride) dst[i] = src[i];
}

__global__ __launch_bounds__(256, 8)
void gdfn_heavy(const float* __restrict__ img,
                const float* __restrict__ noise,
                const float* __restrict__ re_mask,
                const int*   __restrict__ sel,
                const int*   __restrict__ mix_sel,
                float*       __restrict__ out)
{
    constexpr int H = 512, W = 512, HP = 514, WP = 514;
    const int b   = blockIdx.z;
    const int h0  = blockIdx.y * TS;
    const int w0  = blockIdx.x * TS;
    const int tid = threadIdx.x;

    const size_t HWs  = (size_t)H * W;
    const size_t imgB = (size_t)b * 3 * HWs;
    const size_t noiB = (size_t)b * 3 * HP * WP;

    if (!sel[b]) return;   // copy_kernel already wrote out = img

    // ---- mask scan: 8x8x3 tile = 48 float4s, threads 0..47 ----
    int allone = 1;
    if (tid < 48) {
        int c = tid >> 4, r = tid & 15;
        int row = r >> 1, col4 = (r & 1) << 2;
        const float4 m4 = *(const float4*)(re_mask + imgB + (size_t)c * HWs
                                           + (size_t)(h0 + row) * W + (w0 + col4));
        allone = (m4.x == 1.f) & (m4.y == 1.f) & (m4.z == 1.f) & (m4.w == 1.f);
    }
    allone = __syncthreads_and(allone);
    if (allone) return;    // out = img*1 already correct

    // ---- heavy path ----
    const int msel = mix_sel[b];

    // stage-3 per-pixel loads issued early (threads 0..63), overlap stages 0-2
    float img3[3], rm3[3];
    const int ty = tid >> 3, tx = tid & 7;
    const int gy = h0 + ty, gx = w0 + tx;
    const size_t p3 = imgB + (size_t)gy * W + gx;
    if (tid < 64) {
#pragma unroll
        for (int c = 0; c < 3; ++c) {
            img3[c] = img[p3 + c * HWs];
            rm3[c]  = re_mask[p3 + c * HWs];
        }
    }

    __shared__ float s_imgp[3 * PW * PS];   // 2520 B
    __shared__ float s_w   [3 * RW * RW * 9]; // per-ch w, plane0 reused for w3; 15552 B
    __shared__ float s_imgr[RW * RS];       //  624 B
    __shared__ float s_mod [MW * MS];       //  440 B

    // Stage 0: img_p = pad(img,1)+noise over padded [h0-2, h0+11]^2, 588 elems.
#pragma unroll
    for (int it = 0; it < 3; ++it) {
        int idx = tid + it * 256;
        if (idx < 3 * PW * PW) {
            int c  = idx / (PW * PW);
            int r  = idx - c * (PW * PW);
            int ly = r / PW, lx = r - ly * PW;
            int py = h0 - 2 + ly, px = w0 - 2 + lx;   // padded coords
            float v = 0.f;
            if (py >= 0 && py < HP && px >= 0 && px < WP) {
                v = noise[noiB + (size_t)c * HP * WP + (size_t)py * WP + px];
                int iy = py - 1, ix = px - 1;
                if (iy >= 0 && iy < H && ix >= 0 && ix < W)
                    v += img[imgB + (size_t)c * HWs + (size_t)iy * W + ix];
            }
            s_imgp[c * PW * PS + ly * PS + lx] = v;
        }
    }
    __syncthreads();

    // Stage 1a: per (pixel, channel) task (12x12x3 = 432): 9 exps -> s_w[ch][p][k].
    // w = exp(-(x-mean)^2/(2*std^2)), std^2(ddof=1) = ssd/8 => exp(-4 d^2/ssd)
#pragma unroll
    for (int it = 0; it < 2; ++it) {
        int idx = tid + it * 256;
        if (idx < 3 * RW * RW) {
            int ch = idx / (RW * RW), p = idx - ch * (RW * RW);
            int sy = p / RW, sx = p - sy * RW;
            int ry = h0 - 2 + sy, rx = w0 - 2 + sx;
            if (ry >= 0 && ry < H && rx >= 0 && rx < W) {
                const float* sp = &s_imgp[ch * PW * PS + sy * PS + sx];
                float v[9];
                float sum = 0.f;
#pragma unroll
                for (int i = 0; i < 3; ++i)
#pragma unroll
                    for (int j = 0; j < 3; ++j) {
                        float x = sp[i * PS + j];
                        v[i * 3 + j] = x;
                        sum += x;
                    }
                float mean = sum * (1.f / 9.f);
                float ssd = 0.f;
#pragma unroll
                for (int k = 0; k < 9; ++k) { float d = v[k] - mean; ssd += d * d; }
                float inv = -4.f / ssd;
                float* wp = &s_w[(ch * (RW * RW) + p) * 9];
#pragma unroll
                for (int k = 0; k < 9; ++k) {
                    float d = v[k] - mean;
                    wp[k] = expf(d * d * inv);
                }
            }
        }
    }
    __syncthreads();

    // Stage 1b: per pixel (144): w3 = min over ch; img_r = num/den; cache w3 in plane0.
    if (tid < RW * RW) {
        int p = tid;
        int sy = p / RW, sx = p - sy * RW;
        int ry = h0 - 2 + sy, rx = w0 - 2 + sx;
        if (ry >= 0 && ry < H && rx >= 0 && rx < W) {
            const float* wp0 = &s_w[p * 9];
            const float* wp1 = &s_w[(RW * RW + p) * 9];
            const float* wp2 = &s_w[(2 * RW * RW + p) * 9];
            float w3[9];
#pragma unroll
            for (int k = 0; k < 9; ++k)
                w3[k] = fminf(fminf(wp0[k], wp1[k]), wp2[k]);
            const float* sp0 = &s_imgp[0 * PW * PS + sy * PS + sx];
            const float* sp1 = &s_imgp[1 * PW * PS + sy * PS + sx];
            const float* sp2 = &s_imgp[2 * PW * PS + sy * PS + sx];
            float num = 0.f, den = 0.f;
#pragma unroll
            for (int k = 0; k < 9; ++k) {
                int i = k / 3, j = k % 3;
                den += w3[k];
                num += (sp0[i * PS + j] + sp1[i * PS + j] + sp2[i * PS + j]) * w3[k];
            }
            s_imgr[sy * RS + sx] = num / den;
            float* wd = &s_w[p * 9];   // own slot: safe to overwrite after reads
#pragma unroll
            for (int k = 0; k < 9; ++k) wd[k] = w3[k];
        }
    }
    __syncthreads();

    // Stage 2: per pixel (10x10): first-occurrence argmin/argmax over img_r 3x3
    // (OOB = 0.0 exactly); selected weight read from cached w3.
    if (tid < MW * MW) {
        int my = tid / MW, mx = tid - my * MW;
        int qy = h0 - 1 + my, qx = w0 - 1 + mx;
        if (qy >= 0 && qy < H && qx >= 0 && qx < W) {
            float bmin = 0.f, bmax = 0.f;
            int imin = 0, imax = 0;
#pragma unroll
            for (int k = 0; k < 9; ++k) {
                int di = k / 3 - 1, dj = k % 3 - 1;
                int ny = qy + di, nx = qx + dj;
                float val = 0.f;
                if (ny >= 0 && ny < H && nx >= 0 && nx < W)
                    val = s_imgr[(my + 1 + di) * RS + (mx + 1 + dj)];
                if (k == 0) { bmin = val; bmax = val; }
                else {
                    if (val < bmin) { bmin = val; imin = k; }
                    if (val > bmax) { bmax = val; imax = k; }
                }
            }
            int ks = msel ? imax : imin;
            int rp = (my + 1) * RW + (mx + 1);   // stage-1 domain index of q
            s_mod[my * MS + mx] = s_w[rp * 9 + ks];
        }
    }
    __syncthreads();

    // Stage 3: per output pixel (64): img_mod = sum(img_e*m_e)/sum(m_e); blend.
    if (tid < 64) {
        float m[9];
        float mden = 0.f;
#pragma unroll
        for (int k = 0; k < 9; ++k) {
            int di = k / 3 - 1, dj = k % 3 - 1;
            int ny = gy + di, nx = gx + dj;
            float mv = 0.f;
            if (ny >= 0 && ny < H && nx >= 0 && nx < W)
                mv = s_mod[(ty + di + 1) * MS + (tx + dj + 1)];
            m[k] = mv;
            mden += mv;
        }
#pragma unroll
        for (int c = 0; c < 3; ++c) {
            const float* sp = &s_imgp[c * PW * PS + (ty + 2) * PS + (tx + 2)];
            float numc = 0.f;
#pragma unroll
            for (int i = 0; i < 3; ++i)
#pragma unroll
                for (int j = 0; j < 3; ++j)
                    numc += sp[i * PS + j] * m[i * 3 + j];
            float imod = numc / mden;
            float rm   = rm3[c];
            out[p3 + c * HWs] = imod * (1.f - rm) + img3[c] * rm;
        }
    }
}

extern "C" void kernel_launch(void* const* d_in, const int* in_sizes, int n_in,
                              void* d_out, int out_size, void* d_ws, size_t ws_size,
                              hipStream_t stream)
{
    const float* img     = (const float*)d_in[0];
    const float* noise   = (const float*)d_in[1];
    const float* re_mask = (const float*)d_in[2];
    const int*   sel     = (const int*)d_in[3];
    const int*   mix_sel = (const int*)d_in[4];
    float*       out     = (float*)d_out;

    const int B = in_sizes[3];          // 8

    // A: out = img everywhere (heavy kernel overwrites the erase-rect pixels).
    const int n4 = out_size / 4;        // 1572864 float4s
    hipLaunchKernelGGL(copy_kernel, dim3(2048), dim3(256), 0, stream,
                       (const float4*)img, (float4*)out, n4);

    // B: heavy tiles only (same stream -> ordered after A).
    dim3 gridB(512 / TS, 512 / TS, B);  // 64 x 64 x 8
    hipLaunchKernelGGL(gdfn_heavy, gridB, dim3(256), 0, stream,
                       img, noise, re_mask, sel, mix_sel, out);
}

// Round 6
// 132.770 us; speedup vs baseline: 1.0274x; 1.0098x over previous
//
#include <hip/hip_runtime.h>

// ONE fused launch, two roles by blockIdx (candidates first so heavy tiles start early):
//  - bid < NTILES: 8x8 tile candidate for batch b=bid>>12. Exits if !sel[b].
//    If its mask tile is all ones -> writes out=img for its own tile (48 float4).
//    Else -> full heavy pipeline (bit-identical to R5 heavy; w3 cached in LDS).
//  - bid >= NTILES: grid-stride float4 copy img->out, NON-sel batches only.
//  Disjoint writers per pixel -> race-free concurrency; copy streaming hides
//  heavy-block latency (R5 serialized these two phases: ~30us copy + ~20us heavy).
// img_p (padded img+noise) radius 3 -> 14x14/ch; img_r radius 2 -> 12x12;
// img_3d_mod radius 1 -> 10x10.
#define TS 8
#define PW 14
#define PS 15   // LDS row stride (pad +1)
#define RW 12
#define RS 13
#define MW 10
#define MS 11

#define NTILES 32768   // 64 x 64 tiles x 8 batches
#define NCPY   4096    // copy-role blocks

__global__ __launch_bounds__(256, 8)
void gdfn_fused(const float* __restrict__ img,
                const float* __restrict__ noise,
                const float* __restrict__ re_mask,
                const int*   __restrict__ sel,
                const int*   __restrict__ mix_sel,
                float*       __restrict__ out)
{
    constexpr int H = 512, W = 512, HP = 514, WP = 514;
    constexpr int N4B = 3 * H * W / 4;     // float4s per batch = 196608
    const int bid = blockIdx.x;
    const int tid = threadIdx.x;

    // ---------------- copy role: non-sel batches only ----------------
    if (bid >= NTILES) {
        const int cb = bid - NTILES;
        const float4* src = (const float4*)img;
        float4*       dst = (float4*)out;
        const int n4 = 8 * N4B;
        for (int i = cb * 256 + tid; i < n4; i += NCPY * 256) {
            int b = i / N4B;
            if (!sel[b]) dst[i] = src[i];
        }
        return;
    }

    // ---------------- tile-candidate role ----------------
    const int b  = bid >> 12;
    if (!sel[b]) return;                    // copy role owns this batch
    const int t  = bid & 4095;
    const int h0 = (t >> 6) * TS;
    const int w0 = (t & 63) * TS;

    const size_t HWs  = (size_t)H * W;
    const size_t imgB = (size_t)b * 3 * HWs;
    const size_t noiB = (size_t)b * 3 * HP * WP;

    // mask scan + speculative img prefetch: 8x8x3 tile = 48 float4s, threads 0..47
    int allone = 1;
    float4 pimg4;
    size_t tpo = 0;
    if (tid < 48) {
        int c = tid >> 4, r = tid & 15;
        int row = r >> 1, col4 = (r & 1) << 2;
        tpo = imgB + (size_t)c * HWs + (size_t)(h0 + row) * W + (w0 + col4);
        const float4 m4 = *(const float4*)(re_mask + tpo);
        pimg4 = *(const float4*)(img + tpo);
        allone = (m4.x == 1.f) & (m4.y == 1.f) & (m4.z == 1.f) & (m4.w == 1.f);
    }
    allone = __syncthreads_and(allone);
    if (allone) {                           // out = img*1 exactly
        if (tid < 48) *(float4*)(out + tpo) = pimg4;
        return;
    }

    // ---------------- heavy pipeline (bit-identical to R5) ----------------
    const int msel = mix_sel[b];

    // stage-3 per-pixel loads issued early (threads 0..63), overlap stages 0-2
    float img3[3], rm3[3];
    const int ty = tid >> 3, tx = tid & 7;
    const int gy = h0 + ty, gx = w0 + tx;
    const size_t p3 = imgB + (size_t)gy * W + gx;
    if (tid < 64) {
#pragma unroll
        for (int c = 0; c < 3; ++c) {
            img3[c] = img[p3 + c * HWs];
            rm3[c]  = re_mask[p3 + c * HWs];
        }
    }

    __shared__ float s_imgp[3 * PW * PS];     // 2520 B
    __shared__ float s_w   [3 * RW * RW * 9]; // per-ch w; plane0 reused for w3; 15552 B
    __shared__ float s_imgr[RW * RS];         //  624 B
    __shared__ float s_mod [MW * MS];         //  440 B

    // Stage 0: img_p = pad(img,1)+noise over padded [h0-2, h0+11]^2, 588 elems.
#pragma unroll
    for (int it = 0; it < 3; ++it) {
        int idx = tid + it * 256;
        if (idx < 3 * PW * PW) {
            int c  = idx / (PW * PW);
            int r  = idx - c * (PW * PW);
            int ly = r / PW, lx = r - ly * PW;
            int py = h0 - 2 + ly, px = w0 - 2 + lx;   // padded coords
            float v = 0.f;
            if (py >= 0 && py < HP && px >= 0 && px < WP) {
                v = noise[noiB + (size_t)c * HP * WP + (size_t)py * WP + px];
                int iy = py - 1, ix = px - 1;
                if (iy >= 0 && iy < H && ix >= 0 && ix < W)
                    v += img[imgB + (size_t)c * HWs + (size_t)iy * W + ix];
            }
            s_imgp[c * PW * PS + ly * PS + lx] = v;
        }
    }
    __syncthreads();

    // Stage 1a: per (pixel, channel) task (12x12x3 = 432): 9 exps -> s_w[ch][p][k].
    // w = exp(-(x-mean)^2/(2*std^2)), std^2(ddof=1) = ssd/8 => exp(-4 d^2/ssd)
#pragma unroll
    for (int it = 0; it < 2; ++it) {
        int idx = tid + it * 256;
        if (idx < 3 * RW * RW) {
            int ch = idx / (RW * RW), p = idx - ch * (RW * RW);
            int sy = p / RW, sx = p - sy * RW;
            int ry = h0 - 2 + sy, rx = w0 - 2 + sx;
            if (ry >= 0 && ry < H && rx >= 0 && rx < W) {
                const float* sp = &s_imgp[ch * PW * PS + sy * PS + sx];
                float v[9];
                float sum = 0.f;
#pragma unroll
                for (int i = 0; i < 3; ++i)
#pragma unroll
                    for (int j = 0; j < 3; ++j) {
                        float x = sp[i * PS + j];
                        v[i * 3 + j] = x;
                        sum += x;
                    }
                float mean = sum * (1.f / 9.f);
                float ssd = 0.f;
#pragma unroll
                for (int k = 0; k < 9; ++k) { float d = v[k] - mean; ssd += d * d; }
                float inv = -4.f / ssd;
                float* wp = &s_w[(ch * (RW * RW) + p) * 9];
#pragma unroll
                for (int k = 0; k < 9; ++k) {
                    float d = v[k] - mean;
                    wp[k] = expf(d * d * inv);
                }
            }
        }
    }
    __syncthreads();

    // Stage 1b: per pixel (144): w3 = min over ch; img_r = num/den; cache w3 in plane0.
    if (tid < RW * RW) {
        int p = tid;
        int sy = p / RW, sx = p - sy * RW;
        int ry = h0 - 2 + sy, rx = w0 - 2 + sx;
        if (ry >= 0 && ry < H && rx >= 0 && rx < W) {
            const float* wp0 = &s_w[p * 9];
            const float* wp1 = &s_w[(RW * RW + p) * 9];
            const float* wp2 = &s_w[(2 * RW * RW + p) * 9];
            float w3[9];
#pragma unroll
            for (int k = 0; k < 9; ++k)
                w3[k] = fminf(fminf(wp0[k], wp1[k]), wp2[k]);
            const float* sp0 = &s_imgp[0 * PW * PS + sy * PS + sx];
            const float* sp1 = &s_imgp[1 * PW * PS + sy * PS + sx];
            const float* sp2 = &s_imgp[2 * PW * PS + sy * PS + sx];
            float num = 0.f, den = 0.f;
#pragma unroll
            for (int k = 0; k < 9; ++k) {
                int i = k / 3, j = k % 3;
                den += w3[k];
                num += (sp0[i * PS + j] + sp1[i * PS + j] + sp2[i * PS + j]) * w3[k];
            }
            s_imgr[sy * RS + sx] = num / den;
            float* wd = &s_w[p * 9];   // own slot: safe to overwrite after reads
#pragma unroll
            for (int k = 0; k < 9; ++k) wd[k] = w3[k];
        }
    }
    __syncthreads();

    // Stage 2: per pixel (10x10): first-occurrence argmin/argmax over img_r 3x3
    // (OOB = 0.0 exactly); selected weight read from cached w3.
    if (tid < MW * MW) {
        int my = tid / MW, mx = tid - my * MW;
        int qy = h0 - 1 + my, qx = w0 - 1 + mx;
        if (qy >= 0 && qy < H && qx >= 0 && qx < W) {
            float bmin = 0.f, bmax = 0.f;
            int imin = 0, imax = 0;
#pragma unroll
            for (int k = 0; k < 9; ++k) {
                int di = k / 3 - 1, dj = k % 3 - 1;
                int ny = qy + di, nx = qx + dj;
                float val = 0.f;
                if (ny >= 0 && ny < H && nx >= 0 && nx < W)
                    val = s_imgr[(my + 1 + di) * RS + (mx + 1 + dj)];
                if (k == 0) { bmin = val; bmax = val; }
                else {
                    if (val < bmin) { bmin = val; imin = k; }
                    if (val > bmax) { bmax = val; imax = k; }
                }
            }
            int ks = msel ? imax : imin;
            int rp = (my + 1) * RW + (mx + 1);   // stage-1 domain index of q
            s_mod[my * MS + mx] = s_w[rp * 9 + ks];
        }
    }
    __syncthreads();

    // Stage 3: per output pixel (64): img_mod = sum(img_e*m_e)/sum(m_e); blend.
    if (tid < 64) {
        float m[9];
        float mden = 0.f;
#pragma unroll
        for (int k = 0; k < 9; ++k) {
            int di = k / 3 - 1, dj = k % 3 - 1;
            int ny = gy + di, nx = gx + dj;
            float mv = 0.f;
            if (ny >= 0 && ny < H && nx >= 0 && nx < W)
                mv = s_mod[(ty + di + 1) * MS + (tx + dj + 1)];
            m[k] = mv;
            mden += mv;
        }
#pragma unroll
        for (int c = 0; c < 3; ++c) {
            const float* sp = &s_imgp[c * PW * PS + (ty + 2) * PS + (tx + 2)];
            float numc = 0.f;
#pragma unroll
            for (int i = 0; i < 3; ++i)
#pragma unroll
                for (int j = 0; j < 3; ++j)
                    numc += sp[i * PS + j] * m[i * 3 + j];
            float imod = numc / mden;
            float rm   = rm3[c];
            out[p3 + c * HWs] = imod * (1.f - rm) + img3[c] * rm;
        }
    }
}

extern "C" void kernel_launch(void* const* d_in, const int* in_sizes, int n_in,
                              void* d_out, int out_size, void* d_ws, size_t ws_size,
                              hipStream_t stream)
{
    const float* img     = (const float*)d_in[0];
    const float* noise   = (const float*)d_in[1];
    const float* re_mask = (const float*)d_in[2];
    const int*   sel     = (const int*)d_in[3];
    const int*   mix_sel = (const int*)d_in[4];
    float*       out     = (float*)d_out;

    dim3 grid(NTILES + NCPY);   // candidates first -> heavy tiles dispatch early
    hipLaunchKernelGGL(gdfn_fused, grid, dim3(256), 0, stream,
                       img, noise, re_mask, sel, mix_sel, out);
}

// Round 7
// 130.536 us; speedup vs baseline: 1.0449x; 1.0171x over previous
//
#include <hip/hip_runtime.h>

// ONE fused launch, two roles by blockIdx (candidates first so heavy tiles start early):
//  - bid < NTILES: 8x8 tile candidate for batch b=bid>>12. Exits if !sel[b].
//    All-ones mask tile -> writes out=img for its tile. Else -> heavy pipeline.
//  - bid >= NTILES: grid-stride float4 copy img->out, NON-sel batches only.
// R6 heavy-path restructure (vs R5): stage 1 is per-pixel with all 3 channels in
// registers (no 3-plane s_w LDS round-trip; LDS 19.4->8.8 KB, one barrier fewer),
// __expf (v_exp_f32) replaces library expf (argument math unchanged), stage 3 uses
// 192 threads (pixel x channel) for full-wave lanes + coalesced stores.
// img_p (padded img+noise) radius 3 -> 14x14/ch; img_r radius 2 -> 12x12;
// img_3d_mod radius 1 -> 10x10.
#define TS 8
#define PW 14
#define PS 15   // LDS row stride (pad +1)
#define RW 12
#define RS 13
#define MW 10
#define MS 11

#define NTILES 32768   // 64 x 64 tiles x 8 batches
#define NCPY   4096    // copy-role blocks

__global__ __launch_bounds__(256, 8)
void gdfn_fused(const float* __restrict__ img,
                const float* __restrict__ noise,
                const float* __restrict__ re_mask,
                const int*   __restrict__ sel,
                const int*   __restrict__ mix_sel,
                float*       __restrict__ out)
{
    constexpr int H = 512, W = 512, HP = 514, WP = 514;
    constexpr int N4B = 3 * H * W / 4;     // float4s per batch = 196608
    const int bid = blockIdx.x;
    const int tid = threadIdx.x;

    // ---------------- copy role: non-sel batches only ----------------
    if (bid >= NTILES) {
        const int cb = bid - NTILES;
        const float4* src = (const float4*)img;
        float4*       dst = (float4*)out;
        const int n4 = 8 * N4B;
        for (int i = cb * 256 + tid; i < n4; i += NCPY * 256) {
            int b = i / N4B;
            if (!sel[b]) dst[i] = src[i];
        }
        return;
    }

    // ---------------- tile-candidate role ----------------
    const int b  = bid >> 12;
    if (!sel[b]) return;                    // copy role owns this batch
    const int t  = bid & 4095;
    const int h0 = (t >> 6) * TS;
    const int w0 = (t & 63) * TS;

    const size_t HWs  = (size_t)H * W;
    const size_t imgB = (size_t)b * 3 * HWs;
    const size_t noiB = (size_t)b * 3 * HP * WP;

    // mask scan + speculative img prefetch: 8x8x3 tile = 48 float4s, threads 0..47
    int allone = 1;
    float4 pimg4;
    size_t tpo = 0;
    if (tid < 48) {
        int c = tid >> 4, r = tid & 15;
        int row = r >> 1, col4 = (r & 1) << 2;
        tpo = imgB + (size_t)c * HWs + (size_t)(h0 + row) * W + (w0 + col4);
        const float4 m4 = *(const float4*)(re_mask + tpo);
        pimg4 = *(const float4*)(img + tpo);
        allone = (m4.x == 1.f) & (m4.y == 1.f) & (m4.z == 1.f) & (m4.w == 1.f);
    }
    allone = __syncthreads_and(allone);
    if (allone) {                           // out = img*1 exactly
        if (tid < 48) *(float4*)(out + tpo) = pimg4;
        return;
    }

    // ---------------- heavy pipeline ----------------
    const int msel = mix_sel[b];

    // stage-3 per-(pixel,channel) loads issued early (threads 0..191)
    const int c3  = tid >> 6;              // 0..3 (c3==3 inactive in stage 3)
    const int p3i = tid & 63;
    const int t3y = p3i >> 3, t3x = p3i & 7;
    const int g3y = h0 + t3y, g3x = w0 + t3x;
    const size_t o3 = imgB + (size_t)c3 * HWs + (size_t)g3y * W + g3x;
    float img3v = 0.f, rm3v = 0.f;
    if (tid < 192) {
        img3v = img[o3];
        rm3v  = re_mask[o3];
    }

    __shared__ float s_imgp[3 * PW * PS];   // 2520 B
    __shared__ float s_w   [RW * RW * 9];   // w3 per stage-1 pixel, 5184 B
    __shared__ float s_imgr[RW * RS];       //  624 B
    __shared__ float s_mod [MW * MS];       //  440 B

    // Stage 0: img_p = pad(img,1)+noise over padded [h0-2, h0+11]^2, 588 elems.
#pragma unroll
    for (int it = 0; it < 3; ++it) {
        int idx = tid + it * 256;
        if (idx < 3 * PW * PW) {
            int c  = idx / (PW * PW);
            int r  = idx - c * (PW * PW);
            int ly = r / PW, lx = r - ly * PW;
            int py = h0 - 2 + ly, px = w0 - 2 + lx;   // padded coords
            float v = 0.f;
            if (py >= 0 && py < HP && px >= 0 && px < WP) {
                v = noise[noiB + (size_t)c * HP * WP + (size_t)py * WP + px];
                int iy = py - 1, ix = px - 1;
                if (iy >= 0 && iy < H && ix >= 0 && ix < W)
                    v += img[imgB + (size_t)c * HWs + (size_t)iy * W + ix];
            }
            s_imgp[c * PW * PS + ly * PS + lx] = v;
        }
    }
    __syncthreads();

    // Stage 1: per pixel (12x12 = 144 tasks), all 3 channels in registers.
    // w = exp(-(x-mean)^2/(2*std^2)), std^2(ddof=1) = ssd/8 => exp(-4 d^2/ssd)
    // Channel grouping (v0+v1)+v2 and k-order summation match the passing R5 kernel.
    if (tid < RW * RW) {
        int sy = tid / RW, sx = tid - sy * RW;
        int ry = h0 - 2 + sy, rx = w0 - 2 + sx;
        if (ry >= 0 && ry < H && rx >= 0 && rx < W) {
            float w3[9], vs[9];
#pragma unroll
            for (int c = 0; c < 3; ++c) {
                const float* sp = &s_imgp[c * PW * PS + sy * PS + sx];
                float v[9];
                float sum = 0.f;
#pragma unroll
                for (int i = 0; i < 3; ++i)
#pragma unroll
                    for (int j = 0; j < 3; ++j) {
                        float x = sp[i * PS + j];
                        v[i * 3 + j] = x;
                        sum += x;
                    }
                float mean = sum * (1.f / 9.f);
                float ssd = 0.f;
#pragma unroll
                for (int k = 0; k < 9; ++k) { float d = v[k] - mean; ssd += d * d; }
                float inv = -4.f / ssd;
#pragma unroll
                for (int k = 0; k < 9; ++k) {
                    float d  = v[k] - mean;
                    float wv = __expf(d * d * inv);   // native v_exp_f32 path
                    if (c == 0) { w3[k] = wv;              vs[k] = v[k];  }
                    else        { w3[k] = fminf(w3[k], wv); vs[k] += v[k]; }
                }
            }
            float num = 0.f, den = 0.f;
#pragma unroll
            for (int k = 0; k < 9; ++k) {
                den += w3[k];
                num += vs[k] * w3[k];
            }
            s_imgr[sy * RS + sx] = num / den;
            float* wd = &s_w[tid * 9];
#pragma unroll
            for (int k = 0; k < 9; ++k) wd[k] = w3[k];
        }
    }
    __syncthreads();

    // Stage 2: per pixel (10x10): first-occurrence argmin/argmax over img_r 3x3
    // (OOB = 0.0 exactly); selected weight read from cached w3.
    if (tid < MW * MW) {
        int my = tid / MW, mx = tid - my * MW;
        int qy = h0 - 1 + my, qx = w0 - 1 + mx;
        if (qy >= 0 && qy < H && qx >= 0 && qx < W) {
            float bmin = 0.f, bmax = 0.f;
            int imin = 0, imax = 0;
#pragma unroll
            for (int k = 0; k < 9; ++k) {
                int di = k / 3 - 1, dj = k % 3 - 1;
                int ny = qy + di, nx = qx + dj;
                float val = 0.f;
                if (ny >= 0 && ny < H && nx >= 0 && nx < W)
                    val = s_imgr[(my + 1 + di) * RS + (mx + 1 + dj)];
                if (k == 0) { bmin = val; bmax = val; }
                else {
                    if (val < bmin) { bmin = val; imin = k; }
                    if (val > bmax) { bmax = val; imax = k; }
                }
            }
            int ks = msel ? imax : imin;
            int rp = (my + 1) * RW + (mx + 1);   // stage-1 domain index of q
            s_mod[my * MS + mx] = s_w[rp * 9 + ks];
        }
    }
    __syncthreads();

    // Stage 3: per (pixel, channel), 192 threads: img_mod = sum(img_e*m_e)/sum(m_e).
    // mden recomputed per channel is bit-identical (same adds in same order).
    if (tid < 192) {
        float m[9];
        float mden = 0.f;
#pragma unroll
        for (int k = 0; k < 9; ++k) {
            int di = k / 3 - 1, dj = k % 3 - 1;
            int ny = g3y + di, nx = g3x + dj;
            float mv = 0.f;
            if (ny >= 0 && ny < H && nx >= 0 && nx < W)
                mv = s_mod[(t3y + di + 1) * MS + (t3x + dj + 1)];
            m[k] = mv;
            mden += mv;
        }
        const float* sp = &s_imgp[c3 * PW * PS + (t3y + 2) * PS + (t3x + 2)];
        float numc = 0.f;
#pragma unroll
        for (int i = 0; i < 3; ++i)
#pragma unroll
            for (int j = 0; j < 3; ++j)
                numc += sp[i * PS + j] * m[i * 3 + j];
        float imod = numc / mden;
        out[o3] = imod * (1.f - rm3v) + img3v * rm3v;
    }
}

extern "C" void kernel_launch(void* const* d_in, const int* in_sizes, int n_in,
                              void* d_out, int out_size, void* d_ws, size_t ws_size,
                              hipStream_t stream)
{
    const float* img     = (const float*)d_in[0];
    const float* noise   = (const float*)d_in[1];
    const float* re_mask = (const float*)d_in[2];
    const int*   sel     = (const int*)d_in[3];
    const int*   mix_sel = (const int*)d_in[4];
    float*       out     = (float*)d_out;

    dim3 grid(NTILES + NCPY);   // candidates first -> heavy tiles dispatch early
    hipLaunchKernelGGL(gdfn_fused, grid, dim3(256), 0, stream,
                       img, noise, re_mask, sel, mix_sel, out);
}